// Round 1
// baseline (366.365 us; speedup 1.0000x reference)
//
#include <hip/hip_runtime.h>

// RNN LM fused forward on MI355X (gfx950).
// B=1024 batches, T=256 steps, V=256 vocab, H=32 hidden.
// One block per batch element; 256 threads (4 waves).
//   - W_xh (V*H = 32 KiB) staged in LDS once (embedding gather target).
//   - Token row X[b, 0..T) staged in LDS (1 KiB).
//   - W_hq column for v==tid kept in 32 VGPRs per thread (reused 256 steps).
//   - W_hh column for j==tid kept in 32 VGPRs (threads < 32 only use it).
//   - h double-buffered in LDS -> exactly ONE __syncthreads() per step.
// Output write (256 MiB fp32) is the roofline: ~42 us at 6.3 TB/s.

#define B_SZ 1024
#define T_SZ 256
#define V_SZ 256
#define H_SZ 32

__global__ __launch_bounds__(256, 4) void rnnlm_fused(
    const int*   __restrict__ X,      // [B, T]
    const float* __restrict__ W_xh,   // [V, H]
    const float* __restrict__ W_hh,   // [H, H]
    const float* __restrict__ b_h,    // [H]
    const float* __restrict__ W_hq,   // [H, V]
    const float* __restrict__ b_q,    // [V]
    float*       __restrict__ out)    // [B, T, V]
{
    __shared__ float s_wxh[V_SZ * H_SZ];  // 32 KiB embedding table
    __shared__ int   s_tok[T_SZ];         // this batch's token ids
    __shared__ float s_h[2][H_SZ];        // double-buffered hidden state

    const int tid = threadIdx.x;
    const int b   = blockIdx.x;

    // ---- one-time staging ----
    // embedding table: 8192 floats / 256 threads = 32 each, coalesced
    #pragma unroll
    for (int i = 0; i < (V_SZ * H_SZ) / 256; ++i)
        s_wxh[i * 256 + tid] = W_xh[i * 256 + tid];

    // token row for this batch (T == blockDim)
    s_tok[tid] = X[b * T_SZ + tid];

    // W_hq column for my vocab slot v = tid (stride-V loads, coalesced per j)
    float whq[H_SZ];
    #pragma unroll
    for (int j = 0; j < H_SZ; ++j)
        whq[j] = W_hq[j * V_SZ + tid];
    const float bq = b_q[tid];

    // threads < H: W_hh column j = tid, bias, and h_{-1} = 0 into buffer 1
    float whh[H_SZ];
    float bh = 0.0f;
    if (tid < H_SZ) {
        #pragma unroll
        for (int i = 0; i < H_SZ; ++i)
            whh[i] = W_hh[i * H_SZ + tid];
        bh = b_h[tid];
        s_h[1][tid] = 0.0f;   // at t=0, prv buffer is index 1
    }
    __syncthreads();

    float* outp = out + (size_t)b * T_SZ * V_SZ + tid;

    // ---- time loop: 1 sync per step (double-buffered h) ----
    for (int t = 0; t < T_SZ; ++t) {
        const int cur = t & 1;
        const int prv = cur ^ 1;

        if (tid < H_SZ) {
            const int tok = s_tok[t];
            // a_j = e_j + b_h_j + sum_i h_i * W_hh[i][j], 4 partial chains
            float a0 = s_wxh[tok * H_SZ + tid] + bh;
            float a1 = 0.0f, a2 = 0.0f, a3 = 0.0f;
            #pragma unroll
            for (int i = 0; i < H_SZ; i += 4) {
                a0 += s_h[prv][i + 0] * whh[i + 0];
                a1 += s_h[prv][i + 1] * whh[i + 1];
                a2 += s_h[prv][i + 2] * whh[i + 2];
                a3 += s_h[prv][i + 3] * whh[i + 3];
            }
            s_h[cur][tid] = tanhf((a0 + a1) + (a2 + a3));
        }
        __syncthreads();
        // Hazard check: s_h[cur] written pre-sync, read post-sync here and
        // pre-sync next iter (as prv); next write to this buffer is at t+2,
        // which is after sync_{t+1} -> one barrier per step is sufficient.

        // logits: each thread owns v = tid; h broadcast-read from LDS (float4)
        float acc = bq;
        const float4* hv = (const float4*)s_h[cur];
        #pragma unroll
        for (int j = 0; j < H_SZ / 4; ++j) {
            const float4 h4 = hv[j];
            acc += h4.x * whq[4 * j + 0];
            acc += h4.y * whq[4 * j + 1];
            acc += h4.z * whq[4 * j + 2];
            acc += h4.w * whq[4 * j + 3];
        }
        outp[t * V_SZ] = acc;  // coalesced: 256 consecutive floats per block
    }
}

extern "C" void kernel_launch(void* const* d_in, const int* in_sizes, int n_in,
                              void* d_out, int out_size, void* d_ws, size_t ws_size,
                              hipStream_t stream) {
    const int*   X    = (const int*)d_in[0];
    const float* W_xh = (const float*)d_in[1];
    const float* W_hh = (const float*)d_in[2];
    const float* b_h  = (const float*)d_in[3];
    const float* W_hq = (const float*)d_in[4];
    const float* b_q  = (const float*)d_in[5];
    float* out = (float*)d_out;

    rnnlm_fused<<<dim3(B_SZ), dim3(256), 0, stream>>>(X, W_xh, W_hh, b_h, W_hq, b_q, out);
}